// Round 4
// baseline (185.513 us; speedup 1.0000x reference)
//
#include <hip/hip_runtime.h>
#include <stdint.h>

#define NN 8192
#define DD 512
#define BT 256            // output tile (BT x BT)
#define BK 64             // K-step
#define NKT (DD / BK)     // 8
#define NB (NN / BT)      // 32
#define NTILES (NB * (NB + 1) / 2)   // 528
#define GRID 512

typedef short s16x8 __attribute__((ext_vector_type(8)));
typedef float f32x4 __attribute__((ext_vector_type(4)));

static __device__ __forceinline__ short f2bf(float x) {
  union { float f; uint32_t u; } c; c.f = x;
  uint32_t r = c.u + 0x7fffu + ((c.u >> 16) & 1u);   // RNE
  return (short)(r >> 16);
}

static __device__ __forceinline__ int tri_off(int b) {
  return b * NB - (b * (b - 1)) / 2;
}

static __device__ __forceinline__ void gload16(const void* g, void* l) {
  __builtin_amdgcn_global_load_lds(
      (const __attribute__((address_space(1))) void*)g,
      (__attribute__((address_space(3))) void*)l, 16, 0, 0);
}

// 4 waves/block, one row per wave: fp32 -> bf16, sq-norm, init reductions.
__global__ __launch_bounds__(256) void prep_kernel(
    const float* __restrict__ f, short* __restrict__ fb,
    float* __restrict__ sqn, float* __restrict__ pmax,
    float* __restrict__ nmin, float* __restrict__ rmax) {
  int wid = threadIdx.x >> 6, lane = threadIdx.x & 63;
  int row = blockIdx.x * 4 + wid;
  const float4* src = (const float4*)(f + (size_t)row * DD);
  float4 v0 = src[lane * 2];
  float4 v1 = src[lane * 2 + 1];
  float s = v0.x*v0.x + v0.y*v0.y + v0.z*v0.z + v0.w*v0.w
          + v1.x*v1.x + v1.y*v1.y + v1.z*v1.z + v1.w*v1.w;
  s16x8 o;
  o[0]=f2bf(v0.x); o[1]=f2bf(v0.y); o[2]=f2bf(v0.z); o[3]=f2bf(v0.w);
  o[4]=f2bf(v1.x); o[5]=f2bf(v1.y); o[6]=f2bf(v1.z); o[7]=f2bf(v1.w);
  *(s16x8*)&fb[(size_t)row * DD + lane * 8] = o;
  #pragma unroll
  for (int m = 1; m < 64; m <<= 1) s += __shfl_xor(s, m);
  if (lane == 0) {
    sqn[row] = s;
    pmax[row] = 0.f;
    nmin[row] = __int_as_float(0x7f800000);   // +inf
    rmax[row] = 0.f;
  }
}

// 256x256 upper-tri tiles of F*F^T, 8 waves, 4-phase counted-vmcnt pipeline.
// LDS pool: region(buf, mat, khalf) = 256 rows x 32 shorts, k-half-major so
// global_load_lds dests are linear; chunk XOR-swizzle (cp ^ (row>>1)&3)
// applied on BOTH the global source and the ds_read address (rule 21).
__global__ __launch_bounds__(512, 2) void tile_kernel(
    const short* __restrict__ fb, const float* __restrict__ sqn,
    const int* __restrict__ lab,
    float* __restrict__ pmax, float* __restrict__ nmin, float* __restrict__ rmax) {
  __shared__ __align__(16) short pool[65536];     // 128 KB staging (reused for reductions)
  __shared__ float s_sq_r[BT], s_sq_c[BT];
  __shared__ int   s_lb_r[BT], s_lb_c[BT];

  int tid = threadIdx.x;
  int wid = tid >> 6, lane = tid & 63;
  int wr = wid >> 2, wc = wid & 3;                // 2 x 4 wave grid
  int hi = lane >> 4, lo = lane & 15;

  // fragment read offsets (shorts): row*32 + swizzled_chunk*8 within a region
  int cswz = hi ^ ((lo >> 1) & 3);
  int aoff = (wr * 128 + lo) * 32 + cswz * 8;
  int boff = (wc * 64  + lo) * 32 + cswz * 8;

  // staging constants: thread covers slot j*512+tid; row=slot>>2, cp=slot&3;
  // source chunk = cp ^ ((row>>1)&3)  (same for j=0,1 since rows differ by 128)
  int srow = tid >> 2;
  int cpx  = (tid & 3) ^ ((tid >> 3) & 3);

  const float FINF = __int_as_float(0x7f800000);

  for (int L = blockIdx.x; L < NTILES; L += GRID) {
    int t = (L & 7) * (NTILES / 8) + (L >> 3);    // bijective XCD swizzle (528 = 8*66)
    int bi = (int)((65.0f - sqrtf(4225.0f - 8.0f * (float)t)) * 0.5f);
    if (bi < 0) bi = 0;
    if (bi > NB - 1) bi = NB - 1;
    while (bi > 0 && tri_off(bi) > t) --bi;
    while (tri_off(bi + 1) <= t) ++bi;
    int bj = bi + (t - tri_off(bi));
    int brow = bi * BT, bcol = bj * BT;
    bool diag_blk = (bi == bj);

    if (tid < BT) {
      s_sq_r[tid] = sqn[brow + tid];
      s_lb_r[tid] = lab[brow + tid];
      s_sq_c[tid] = sqn[bcol + tid];
      s_lb_c[tid] = lab[bcol + tid];
    }

    const short* gA0 = fb + (size_t)(brow + srow) * DD + cpx * 8;
    const short* gB0 = fb + (size_t)(bcol + srow) * DD + cpx * 8;

#define STAGE(bufb, mat, kh, ktn) do {                                        \
    const short* g_ = ((mat) ? gB0 : gA0) + (ktn) * BK + (kh) * 32;           \
    short* d_ = pool + (((((bufb) * 2 + (mat)) * 2) + (kh)) * 8192) + tid * 8;\
    gload16(g_, d_);                                                          \
    gload16(g_ + 128 * DD, d_ + 4096);                                        \
  } while (0)

    f32x4 acc[8][4];
    #pragma unroll
    for (int m = 0; m < 8; ++m)
      #pragma unroll
      for (int n = 0; n < 4; ++n) acc[m][n] = (f32x4)(0.f);

    // prologue: stage K-tile 0 (units in consumption order: A-k0, B-k0, A-k1, B-k1)
    STAGE(0, 0, 0, 0); STAGE(0, 1, 0, 0); STAGE(0, 0, 1, 0); STAGE(0, 1, 1, 0);

    for (int kt = 0; kt < NKT; ++kt) {
      int cur = kt & 1, nxt = cur ^ 1;
      const short* A0 = pool + ((cur * 2 + 0) * 2 + 0) * 8192;
      const short* A1 = pool + ((cur * 2 + 0) * 2 + 1) * 8192;
      const short* B0 = pool + ((cur * 2 + 1) * 2 + 0) * 8192;
      const short* B1 = pool + ((cur * 2 + 1) * 2 + 1) * 8192;
      bool more = (kt + 1 < NKT);
      s16x8 af[4], bf0[4], bf1[4];

      // ---- P0: needs A-k0, B-k0 landed; u(t,2),u(t,3) may stay in flight ----
      asm volatile("s_waitcnt vmcnt(4)" ::: "memory");
      __builtin_amdgcn_s_barrier();
      __builtin_amdgcn_sched_barrier(0);
      #pragma unroll
      for (int n = 0; n < 4; ++n) bf0[n] = *(const s16x8*)(B0 + boff + n * 512);
      #pragma unroll
      for (int m = 0; m < 4; ++m) af[m] = *(const s16x8*)(A0 + aoff + m * 512);
      if (more) STAGE(nxt, 0, 0, kt + 1);
      __builtin_amdgcn_s_barrier();
      asm volatile("s_waitcnt lgkmcnt(0)");
      __builtin_amdgcn_s_setprio(1);
      #pragma unroll
      for (int m = 0; m < 4; ++m)
        #pragma unroll
        for (int n = 0; n < 4; ++n)
          acc[m][n] = __builtin_amdgcn_mfma_f32_16x16x32_bf16(af[m], bf0[n], acc[m][n], 0, 0, 0);
      __builtin_amdgcn_s_setprio(0);

      // ---- P1: A rows m4-7, k0 ----
      #pragma unroll
      for (int m = 0; m < 4; ++m) af[m] = *(const s16x8*)(A0 + aoff + (m + 4) * 512);
      if (more) STAGE(nxt, 1, 0, kt + 1);
      __builtin_amdgcn_s_barrier();
      asm volatile("s_waitcnt lgkmcnt(0)");
      __builtin_amdgcn_s_setprio(1);
      #pragma unroll
      for (int m = 0; m < 4; ++m)
        #pragma unroll
        for (int n = 0; n < 4; ++n)
          acc[m + 4][n] = __builtin_amdgcn_mfma_f32_16x16x32_bf16(af[m], bf0[n], acc[m + 4][n], 0, 0, 0);
      __builtin_amdgcn_s_setprio(0);

      // ---- P2: needs A-k1, B-k1 landed; u(t+1,0),u(t+1,1) may stay in flight ----
      if (kt == NKT - 1) asm volatile("s_waitcnt vmcnt(0)" ::: "memory");
      else               asm volatile("s_waitcnt vmcnt(4)" ::: "memory");
      __builtin_amdgcn_s_barrier();
      __builtin_amdgcn_sched_barrier(0);
      #pragma unroll
      for (int n = 0; n < 4; ++n) bf1[n] = *(const s16x8*)(B1 + boff + n * 512);
      #pragma unroll
      for (int m = 0; m < 4; ++m) af[m] = *(const s16x8*)(A1 + aoff + m * 512);
      if (more) STAGE(nxt, 0, 1, kt + 1);
      __builtin_amdgcn_s_barrier();
      asm volatile("s_waitcnt lgkmcnt(0)");
      __builtin_amdgcn_s_setprio(1);
      #pragma unroll
      for (int m = 0; m < 4; ++m)
        #pragma unroll
        for (int n = 0; n < 4; ++n)
          acc[m][n] = __builtin_amdgcn_mfma_f32_16x16x32_bf16(af[m], bf1[n], acc[m][n], 0, 0, 0);
      __builtin_amdgcn_s_setprio(0);

      // ---- P3: A rows m4-7, k1 ----
      #pragma unroll
      for (int m = 0; m < 4; ++m) af[m] = *(const s16x8*)(A1 + aoff + (m + 4) * 512);
      if (more) STAGE(nxt, 1, 1, kt + 1);
      __builtin_amdgcn_s_barrier();
      asm volatile("s_waitcnt lgkmcnt(0)");
      __builtin_amdgcn_s_setprio(1);
      #pragma unroll
      for (int m = 0; m < 4; ++m)
        #pragma unroll
        for (int n = 0; n < 4; ++n)
          acc[m + 4][n] = __builtin_amdgcn_mfma_f32_16x16x32_bf16(af[m], bf1[n], acc[m + 4][n], 0, 0, 0);
      __builtin_amdgcn_s_setprio(0);
    }

    __syncthreads();   // full drain; pool is now reusable for reductions

    // reductions in squared-distance space; pool aliased:
    // rowred[3][4][256] at pool+0 (12KB), colred[3][2][256] after it (6KB)
    float* rowred = (float*)pool;
    float* colred = (float*)pool + 3 * 4 * 256;

    float sqc[4]; int lbc[4];
    #pragma unroll
    for (int n = 0; n < 4; ++n) {
      int ct = wc * 64 + n * 16 + lo;
      sqc[n] = s_sq_c[ct];
      lbc[n] = s_lb_c[ct];
    }
    float cvp[4], cvn[4], cvr[4];
    #pragma unroll
    for (int n = 0; n < 4; ++n) { cvp[n] = 0.f; cvn[n] = FINF; cvr[n] = 0.f; }

    #pragma unroll
    for (int m = 0; m < 8; ++m) {
      #pragma unroll
      for (int rg = 0; rg < 4; ++rg) {
        int rt = wr * 128 + m * 16 + hi * 4 + rg;
        float sqi = s_sq_r[rt];
        int   li  = s_lb_r[rt];
        float vp = 0.f, vn = FINF, vr = 0.f;
        #pragma unroll
        for (int n = 0; n < 4; ++n) {
          float g = acc[m][n][rg];
          float v = fmaxf(sqi + sqc[n] - 2.0f * g, 0.f);
          if (diag_blk && rt == wc * 64 + n * 16 + lo) v = 0.f;   // diagonal
          bool same = (li == lbc[n]);
          float vs = same ? v : 0.f;
          float vd = same ? FINF : v;
          vr = fmaxf(vr, v);   cvr[n] = fmaxf(cvr[n], v);
          vp = fmaxf(vp, vs);  cvp[n] = fmaxf(cvp[n], vs);
          vn = fminf(vn, vd);  cvn[n] = fminf(cvn[n], vd);
        }
        #pragma unroll
        for (int msk = 1; msk < 16; msk <<= 1) {
          vr = fmaxf(vr, __shfl_xor(vr, msk));
          vp = fmaxf(vp, __shfl_xor(vp, msk));
          vn = fminf(vn, __shfl_xor(vn, msk));
        }
        if (lo == 0) {
          rowred[(0 * 4 + wc) * 256 + rt] = vp;
          rowred[(1 * 4 + wc) * 256 + rt] = vn;
          rowred[(2 * 4 + wc) * 256 + rt] = vr;
        }
      }
    }
    #pragma unroll
    for (int n = 0; n < 4; ++n) {
      #pragma unroll
      for (int msk = 16; msk < 64; msk <<= 1) {
        cvr[n] = fmaxf(cvr[n], __shfl_xor(cvr[n], msk));
        cvp[n] = fmaxf(cvp[n], __shfl_xor(cvp[n], msk));
        cvn[n] = fminf(cvn[n], __shfl_xor(cvn[n], msk));
      }
      if (hi == 0) {
        int ct = wc * 64 + n * 16 + lo;
        colred[(0 * 2 + wr) * 256 + ct] = cvp[n];
        colred[(1 * 2 + wr) * 256 + ct] = cvn[n];
        colred[(2 * 2 + wr) * 256 + ct] = cvr[n];
      }
    }
    __syncthreads();
    if (tid < BT) {
      float p = rowred[(0 * 4 + 0) * 256 + tid];
      float n_ = rowred[(1 * 4 + 0) * 256 + tid];
      float r = rowred[(2 * 4 + 0) * 256 + tid];
      #pragma unroll
      for (int w = 1; w < 4; ++w) {
        p  = fmaxf(p,  rowred[(0 * 4 + w) * 256 + tid]);
        n_ = fminf(n_, rowred[(1 * 4 + w) * 256 + tid]);
        r  = fmaxf(r,  rowred[(2 * 4 + w) * 256 + tid]);
      }
      int gi = brow + tid;
      atomicMax((int*)&pmax[gi], __float_as_int(p));
      atomicMin((int*)&nmin[gi], __float_as_int(n_));
      atomicMax((int*)&rmax[gi], __float_as_int(r));

      float cp_ = fmaxf(colred[(0 * 2 + 0) * 256 + tid], colred[(0 * 2 + 1) * 256 + tid]);
      float cn_ = fminf(colred[(1 * 2 + 0) * 256 + tid], colred[(1 * 2 + 1) * 256 + tid]);
      float cr_ = fmaxf(colred[(2 * 2 + 0) * 256 + tid], colred[(2 * 2 + 1) * 256 + tid]);
      int gj = bcol + tid;
      atomicMax((int*)&pmax[gj], __float_as_int(cp_));
      atomicMin((int*)&nmin[gj], __float_as_int(cn_));
      atomicMax((int*)&rmax[gj], __float_as_int(cr_));
    }
    __syncthreads();   // pool + s_sq/s_lb safe to reuse next tile
  }
#undef STAGE
}

__global__ __launch_bounds__(256) void finalize_kernel(
    const float* __restrict__ pmax, const float* __restrict__ nmin,
    const float* __restrict__ rmax, float* __restrict__ out) {
  int i = blockIdx.x * blockDim.x + threadIdx.x;
  if (i < NN) {
    out[2 * i]     = sqrtf(pmax[i]);                  // back to distance space
    out[2 * i + 1] = sqrtf(fminf(nmin[i], rmax[i]));  // no-negative fallback
  }
}

extern "C" void kernel_launch(void* const* d_in, const int* in_sizes, int n_in,
                              void* d_out, int out_size, void* d_ws, size_t ws_size,
                              hipStream_t stream) {
  const float* feat = (const float*)d_in[0];
  const int*   lab  = (const int*)d_in[1];
  float* out = (float*)d_out;

  char* ws = (char*)d_ws;
  short* fb   = (short*)ws;                                  // 8192*512*2 = 8388608 B
  float* sqn  = (float*)(ws + 8388608);                      // 32768 B
  float* pmax = (float*)(ws + 8388608 + 32768);              // 32768 B
  float* nmin = (float*)(ws + 8388608 + 2 * 32768);          // 32768 B
  float* rmax = (float*)(ws + 8388608 + 3 * 32768);          // 32768 B

  prep_kernel<<<NN / 4, 256, 0, stream>>>(feat, fb, sqn, pmax, nmin, rmax);
  tile_kernel<<<GRID, 512, 0, stream>>>(fb, sqn, lab, pmax, nmin, rmax);
  finalize_kernel<<<(NN + 255) / 256, 256, 0, stream>>>(pmax, nmin, rmax, out);
}

// Round 5
// 184.889 us; speedup vs baseline: 1.0034x; 1.0034x over previous
//
#include <hip/hip_runtime.h>
#include <stdint.h>

#define NN 8192
#define DD 512
#define BT 256            // output tile (BT x BT)
#define BK 64             // K-step
#define NKT (DD / BK)     // 8
#define NB (NN / BT)      // 32
#define NTILES (NB * (NB + 1) / 2)   // 528
#define GRID 512

typedef short s16x8 __attribute__((ext_vector_type(8)));
typedef float f32x4 __attribute__((ext_vector_type(4)));

static __device__ __forceinline__ short f2bf(float x) {
  union { float f; uint32_t u; } c; c.f = x;
  uint32_t r = c.u + 0x7fffu + ((c.u >> 16) & 1u);   // RNE
  return (short)(r >> 16);
}

static __device__ __forceinline__ int tri_off(int b) {
  return b * NB - (b * (b - 1)) / 2;
}

static __device__ __forceinline__ void gload16(const void* g, void* l) {
  __builtin_amdgcn_global_load_lds(
      (const __attribute__((address_space(1))) void*)g,
      (__attribute__((address_space(3))) void*)l, 16, 0, 0);
}

// 4 waves/block, one row per wave: fp32 -> bf16, sq-norm, init reductions.
__global__ __launch_bounds__(256) void prep_kernel(
    const float* __restrict__ f, short* __restrict__ fb,
    float* __restrict__ sqn, float* __restrict__ pmax,
    float* __restrict__ nmin, float* __restrict__ rmax) {
  int wid = threadIdx.x >> 6, lane = threadIdx.x & 63;
  int row = blockIdx.x * 4 + wid;
  const float4* src = (const float4*)(f + (size_t)row * DD);
  float4 v0 = src[lane * 2];
  float4 v1 = src[lane * 2 + 1];
  float s = v0.x*v0.x + v0.y*v0.y + v0.z*v0.z + v0.w*v0.w
          + v1.x*v1.x + v1.y*v1.y + v1.z*v1.z + v1.w*v1.w;
  s16x8 o;
  o[0]=f2bf(v0.x); o[1]=f2bf(v0.y); o[2]=f2bf(v0.z); o[3]=f2bf(v0.w);
  o[4]=f2bf(v1.x); o[5]=f2bf(v1.y); o[6]=f2bf(v1.z); o[7]=f2bf(v1.w);
  *(s16x8*)&fb[(size_t)row * DD + lane * 8] = o;
  #pragma unroll
  for (int m = 1; m < 64; m <<= 1) s += __shfl_xor(s, m);
  if (lane == 0) {
    sqn[row] = s;
    pmax[row] = 0.f;
    nmin[row] = __int_as_float(0x7f800000);   // +inf
    rmax[row] = 0.f;
  }
}

// 256x256 upper-tri tiles of F*F^T, 8 waves, 4-phase counted-vmcnt pipeline.
// __launch_bounds__(512,1): 1 block/CU -> 256-VGPR cap; acc[8][4] (128 VGPR)
// stays in registers (R4's (512,2) capped at 128 VGPR and spilled acc).
__global__ __launch_bounds__(512, 1) void tile_kernel(
    const short* __restrict__ fb, const float* __restrict__ sqn,
    const int* __restrict__ lab,
    float* __restrict__ pmax, float* __restrict__ nmin, float* __restrict__ rmax) {
  __shared__ __align__(16) short pool[65536];     // 128 KB staging (reused for reductions)
  __shared__ float s_sq_r[BT], s_sq_c[BT];
  __shared__ int   s_lb_r[BT], s_lb_c[BT];

  int tid = threadIdx.x;
  int wid = tid >> 6, lane = tid & 63;
  int wr = wid >> 2, wc = wid & 3;                // 2 x 4 wave grid
  int hi = lane >> 4, lo = lane & 15;

  // fragment read offsets (shorts): row*32 + swizzled_chunk*8 within a region
  int cswz = hi ^ ((lo >> 1) & 3);
  int aoff = (wr * 128 + lo) * 32 + cswz * 8;
  int boff = (wc * 64  + lo) * 32 + cswz * 8;

  // staging constants: thread covers slot j*512+tid; row=slot>>2, cp=slot&3;
  // source chunk = cp ^ ((row>>1)&3)  (same for j=0,1 since rows differ by 128)
  int srow = tid >> 2;
  int cpx  = (tid & 3) ^ ((tid >> 3) & 3);

  const float FINF = __int_as_float(0x7f800000);

  for (int L = blockIdx.x; L < NTILES; L += GRID) {
    int t = (L & 7) * (NTILES / 8) + (L >> 3);    // bijective XCD swizzle (528 = 8*66)
    int bi = (int)((65.0f - sqrtf(4225.0f - 8.0f * (float)t)) * 0.5f);
    if (bi < 0) bi = 0;
    if (bi > NB - 1) bi = NB - 1;
    while (bi > 0 && tri_off(bi) > t) --bi;
    while (tri_off(bi + 1) <= t) ++bi;
    int bj = bi + (t - tri_off(bi));
    int brow = bi * BT, bcol = bj * BT;
    bool diag_blk = (bi == bj);

    if (tid < BT) {
      s_sq_r[tid] = sqn[brow + tid];
      s_lb_r[tid] = lab[brow + tid];
      s_sq_c[tid] = sqn[bcol + tid];
      s_lb_c[tid] = lab[bcol + tid];
    }

    const short* gA0 = fb + (size_t)(brow + srow) * DD + cpx * 8;
    const short* gB0 = fb + (size_t)(bcol + srow) * DD + cpx * 8;

#define STAGE(bufb, mat, kh, ktn) do {                                        \
    const short* g_ = ((mat) ? gB0 : gA0) + (ktn) * BK + (kh) * 32;           \
    short* d_ = pool + (((((bufb) * 2 + (mat)) * 2) + (kh)) * 8192) + tid * 8;\
    gload16(g_, d_);                                                          \
    gload16(g_ + 128 * DD, d_ + 4096);                                        \
  } while (0)

    f32x4 acc[8][4];
    #pragma unroll
    for (int m = 0; m < 8; ++m)
      #pragma unroll
      for (int n = 0; n < 4; ++n) acc[m][n] = (f32x4)(0.f);

    // prologue: stage K-tile 0 (units in consumption order: A-k0, B-k0, A-k1, B-k1)
    STAGE(0, 0, 0, 0); STAGE(0, 1, 0, 0); STAGE(0, 0, 1, 0); STAGE(0, 1, 1, 0);

    for (int kt = 0; kt < NKT; ++kt) {
      int cur = kt & 1, nxt = cur ^ 1;
      const short* A0 = pool + ((cur * 2 + 0) * 2 + 0) * 8192;
      const short* A1 = pool + ((cur * 2 + 0) * 2 + 1) * 8192;
      const short* B0 = pool + ((cur * 2 + 1) * 2 + 0) * 8192;
      const short* B1 = pool + ((cur * 2 + 1) * 2 + 1) * 8192;
      bool more = (kt + 1 < NKT);
      s16x8 af[4], bf0[4], bf1[4];

      // ---- P0: needs A-k0, B-k0 landed; u(t,2),u(t,3) may stay in flight ----
      asm volatile("s_waitcnt vmcnt(4)" ::: "memory");
      __builtin_amdgcn_s_barrier();
      __builtin_amdgcn_sched_barrier(0);
      #pragma unroll
      for (int n = 0; n < 4; ++n) bf0[n] = *(const s16x8*)(B0 + boff + n * 512);
      #pragma unroll
      for (int m = 0; m < 4; ++m) af[m] = *(const s16x8*)(A0 + aoff + m * 512);
      if (more) STAGE(nxt, 0, 0, kt + 1);
      __builtin_amdgcn_s_barrier();
      asm volatile("s_waitcnt lgkmcnt(0)");
      __builtin_amdgcn_s_setprio(1);
      #pragma unroll
      for (int m = 0; m < 4; ++m)
        #pragma unroll
        for (int n = 0; n < 4; ++n)
          acc[m][n] = __builtin_amdgcn_mfma_f32_16x16x32_bf16(af[m], bf0[n], acc[m][n], 0, 0, 0);
      __builtin_amdgcn_s_setprio(0);

      // ---- P1: A rows m4-7, k0 ----
      #pragma unroll
      for (int m = 0; m < 4; ++m) af[m] = *(const s16x8*)(A0 + aoff + (m + 4) * 512);
      if (more) STAGE(nxt, 1, 0, kt + 1);
      __builtin_amdgcn_s_barrier();
      asm volatile("s_waitcnt lgkmcnt(0)");
      __builtin_amdgcn_s_setprio(1);
      #pragma unroll
      for (int m = 0; m < 4; ++m)
        #pragma unroll
        for (int n = 0; n < 4; ++n)
          acc[m + 4][n] = __builtin_amdgcn_mfma_f32_16x16x32_bf16(af[m], bf0[n], acc[m + 4][n], 0, 0, 0);
      __builtin_amdgcn_s_setprio(0);

      // ---- P2: needs A-k1, B-k1 landed; u(t+1,0),u(t+1,1) may stay in flight ----
      if (kt == NKT - 1) asm volatile("s_waitcnt vmcnt(0)" ::: "memory");
      else               asm volatile("s_waitcnt vmcnt(4)" ::: "memory");
      __builtin_amdgcn_s_barrier();
      __builtin_amdgcn_sched_barrier(0);
      #pragma unroll
      for (int n = 0; n < 4; ++n) bf1[n] = *(const s16x8*)(B1 + boff + n * 512);
      #pragma unroll
      for (int m = 0; m < 4; ++m) af[m] = *(const s16x8*)(A1 + aoff + m * 512);
      if (more) STAGE(nxt, 0, 1, kt + 1);
      __builtin_amdgcn_s_barrier();
      asm volatile("s_waitcnt lgkmcnt(0)");
      __builtin_amdgcn_s_setprio(1);
      #pragma unroll
      for (int m = 0; m < 4; ++m)
        #pragma unroll
        for (int n = 0; n < 4; ++n)
          acc[m][n] = __builtin_amdgcn_mfma_f32_16x16x32_bf16(af[m], bf1[n], acc[m][n], 0, 0, 0);
      __builtin_amdgcn_s_setprio(0);

      // ---- P3: A rows m4-7, k1 ----
      #pragma unroll
      for (int m = 0; m < 4; ++m) af[m] = *(const s16x8*)(A1 + aoff + (m + 4) * 512);
      if (more) STAGE(nxt, 1, 1, kt + 1);
      __builtin_amdgcn_s_barrier();
      asm volatile("s_waitcnt lgkmcnt(0)");
      __builtin_amdgcn_s_setprio(1);
      #pragma unroll
      for (int m = 0; m < 4; ++m)
        #pragma unroll
        for (int n = 0; n < 4; ++n)
          acc[m + 4][n] = __builtin_amdgcn_mfma_f32_16x16x32_bf16(af[m], bf1[n], acc[m + 4][n], 0, 0, 0);
      __builtin_amdgcn_s_setprio(0);
    }

    __syncthreads();   // full drain; pool is now reusable for reductions

    // reductions in squared-distance space; pool aliased:
    // rowred[3][4][256] at pool+0 (12KB), colred[3][2][256] after it (6KB)
    float* rowred = (float*)pool;
    float* colred = (float*)pool + 3 * 4 * 256;

    float sqc[4]; int lbc[4];
    #pragma unroll
    for (int n = 0; n < 4; ++n) {
      int ct = wc * 64 + n * 16 + lo;
      sqc[n] = s_sq_c[ct];
      lbc[n] = s_lb_c[ct];
    }
    float cvp[4], cvn[4], cvr[4];
    #pragma unroll
    for (int n = 0; n < 4; ++n) { cvp[n] = 0.f; cvn[n] = FINF; cvr[n] = 0.f; }

    #pragma unroll
    for (int m = 0; m < 8; ++m) {
      #pragma unroll
      for (int rg = 0; rg < 4; ++rg) {
        int rt = wr * 128 + m * 16 + hi * 4 + rg;
        float sqi = s_sq_r[rt];
        int   li  = s_lb_r[rt];
        float vp = 0.f, vn = FINF, vr = 0.f;
        #pragma unroll
        for (int n = 0; n < 4; ++n) {
          float g = acc[m][n][rg];
          float v = fmaxf(sqi + sqc[n] - 2.0f * g, 0.f);
          if (diag_blk && rt == wc * 64 + n * 16 + lo) v = 0.f;   // diagonal
          bool same = (li == lbc[n]);
          float vs = same ? v : 0.f;
          float vd = same ? FINF : v;
          vr = fmaxf(vr, v);   cvr[n] = fmaxf(cvr[n], v);
          vp = fmaxf(vp, vs);  cvp[n] = fmaxf(cvp[n], vs);
          vn = fminf(vn, vd);  cvn[n] = fminf(cvn[n], vd);
        }
        #pragma unroll
        for (int msk = 1; msk < 16; msk <<= 1) {
          vr = fmaxf(vr, __shfl_xor(vr, msk));
          vp = fmaxf(vp, __shfl_xor(vp, msk));
          vn = fminf(vn, __shfl_xor(vn, msk));
        }
        if (lo == 0) {
          rowred[(0 * 4 + wc) * 256 + rt] = vp;
          rowred[(1 * 4 + wc) * 256 + rt] = vn;
          rowred[(2 * 4 + wc) * 256 + rt] = vr;
        }
      }
    }
    #pragma unroll
    for (int n = 0; n < 4; ++n) {
      #pragma unroll
      for (int msk = 16; msk < 64; msk <<= 1) {
        cvr[n] = fmaxf(cvr[n], __shfl_xor(cvr[n], msk));
        cvp[n] = fmaxf(cvp[n], __shfl_xor(cvp[n], msk));
        cvn[n] = fminf(cvn[n], __shfl_xor(cvn[n], msk));
      }
      if (hi == 0) {
        int ct = wc * 64 + n * 16 + lo;
        colred[(0 * 2 + wr) * 256 + ct] = cvp[n];
        colred[(1 * 2 + wr) * 256 + ct] = cvn[n];
        colred[(2 * 2 + wr) * 256 + ct] = cvr[n];
      }
    }
    __syncthreads();
    if (tid < BT) {
      float p = rowred[(0 * 4 + 0) * 256 + tid];
      float n_ = rowred[(1 * 4 + 0) * 256 + tid];
      float r = rowred[(2 * 4 + 0) * 256 + tid];
      #pragma unroll
      for (int w = 1; w < 4; ++w) {
        p  = fmaxf(p,  rowred[(0 * 4 + w) * 256 + tid]);
        n_ = fminf(n_, rowred[(1 * 4 + w) * 256 + tid]);
        r  = fmaxf(r,  rowred[(2 * 4 + w) * 256 + tid]);
      }
      int gi = brow + tid;
      atomicMax((int*)&pmax[gi], __float_as_int(p));
      atomicMin((int*)&nmin[gi], __float_as_int(n_));
      atomicMax((int*)&rmax[gi], __float_as_int(r));

      float cp_ = fmaxf(colred[(0 * 2 + 0) * 256 + tid], colred[(0 * 2 + 1) * 256 + tid]);
      float cn_ = fminf(colred[(1 * 2 + 0) * 256 + tid], colred[(1 * 2 + 1) * 256 + tid]);
      float cr_ = fmaxf(colred[(2 * 2 + 0) * 256 + tid], colred[(2 * 2 + 1) * 256 + tid]);
      int gj = bcol + tid;
      atomicMax((int*)&pmax[gj], __float_as_int(cp_));
      atomicMin((int*)&nmin[gj], __float_as_int(cn_));
      atomicMax((int*)&rmax[gj], __float_as_int(cr_));
    }
    __syncthreads();   // pool + s_sq/s_lb safe to reuse next tile
  }
#undef STAGE
}

__global__ __launch_bounds__(256) void finalize_kernel(
    const float* __restrict__ pmax, const float* __restrict__ nmin,
    const float* __restrict__ rmax, float* __restrict__ out) {
  int i = blockIdx.x * blockDim.x + threadIdx.x;
  if (i < NN) {
    out[2 * i]     = sqrtf(pmax[i]);                  // back to distance space
    out[2 * i + 1] = sqrtf(fminf(nmin[i], rmax[i]));  // no-negative fallback
  }
}

extern "C" void kernel_launch(void* const* d_in, const int* in_sizes, int n_in,
                              void* d_out, int out_size, void* d_ws, size_t ws_size,
                              hipStream_t stream) {
  const float* feat = (const float*)d_in[0];
  const int*   lab  = (const int*)d_in[1];
  float* out = (float*)d_out;

  char* ws = (char*)d_ws;
  short* fb   = (short*)ws;                                  // 8192*512*2 = 8388608 B
  float* sqn  = (float*)(ws + 8388608);                      // 32768 B
  float* pmax = (float*)(ws + 8388608 + 32768);              // 32768 B
  float* nmin = (float*)(ws + 8388608 + 2 * 32768);          // 32768 B
  float* rmax = (float*)(ws + 8388608 + 3 * 32768);          // 32768 B

  prep_kernel<<<NN / 4, 256, 0, stream>>>(feat, fb, sqn, pmax, nmin, rmax);
  tile_kernel<<<GRID, 512, 0, stream>>>(fb, sqn, lab, pmax, nmin, rmax);
  finalize_kernel<<<(NN + 255) / 256, 256, 0, stream>>>(pmax, nmin, rmax, out);
}

// Round 6
// 144.009 us; speedup vs baseline: 1.2882x; 1.2839x over previous
//
#include <hip/hip_runtime.h>
#include <stdint.h>

#define NN 8192
#define DD 512
#define BM 128
#define BK 64             // bf16 elements per K-step = 128 B rows in LDS
#define NKT (DD / BK)     // 8
#define NB 64             // NN / BM
#define NTILES 2080       // NB*(NB+1)/2 upper-triangular tiles

typedef short s16x8 __attribute__((ext_vector_type(8)));
typedef float f32x4 __attribute__((ext_vector_type(4)));

static __device__ __forceinline__ short f2bf(float x) {
  union { float f; uint32_t u; } c; c.f = x;
  uint32_t r = c.u + 0x7fffu + ((c.u >> 16) & 1u);   // RNE
  return (short)(r >> 16);
}

static __device__ __forceinline__ int tri_off(int b) {
  return b * NB - (b * (b - 1)) / 2;
}

static __device__ __forceinline__ void gload16(const void* g, void* l) {
  __builtin_amdgcn_global_load_lds(
      (const __attribute__((address_space(1))) void*)g,
      (__attribute__((address_space(3))) void*)l, 16, 0, 0);
}

// 4 waves/block, one row per wave: fp32 -> bf16, sq-norm, init reductions.
__global__ __launch_bounds__(256) void prep_kernel(
    const float* __restrict__ f, short* __restrict__ fb,
    float* __restrict__ sqn, float* __restrict__ pmax,
    float* __restrict__ nmin, float* __restrict__ rmax) {
  int wid = threadIdx.x >> 6, lane = threadIdx.x & 63;
  int row = blockIdx.x * 4 + wid;
  const float4* src = (const float4*)(f + (size_t)row * DD);
  float4 v0 = src[lane * 2];
  float4 v1 = src[lane * 2 + 1];
  float s = v0.x*v0.x + v0.y*v0.y + v0.z*v0.z + v0.w*v0.w
          + v1.x*v1.x + v1.y*v1.y + v1.z*v1.z + v1.w*v1.w;
  s16x8 o;
  o[0]=f2bf(v0.x); o[1]=f2bf(v0.y); o[2]=f2bf(v0.z); o[3]=f2bf(v0.w);
  o[4]=f2bf(v1.x); o[5]=f2bf(v1.y); o[6]=f2bf(v1.z); o[7]=f2bf(v1.w);
  *(s16x8*)&fb[(size_t)row * DD + lane * 8] = o;
  #pragma unroll
  for (int m = 1; m < 64; m <<= 1) s += __shfl_xor(s, m);
  if (lane == 0) {
    sqn[row] = s;
    pmax[row] = 0.f;
    nmin[row] = __int_as_float(0x7f800000);   // +inf
    rmax[row] = 0.f;
  }
}

// Upper-triangular 128x128 tiles of F*F^T via bf16 MFMA + global_load_lds
// staging (linear LDS dest, swizzled global source + swizzled ds_read).
// R2 structure (proven clean); epilogue reduces in SQUARED-distance space.
// LDS = 40960 B exactly -> 4 blocks/CU; VGPR 68 -> no cap pressure.
__global__ __launch_bounds__(256, 4) void tile_kernel(
    const short* __restrict__ fb, const float* __restrict__ sqn,
    const int* __restrict__ lab,
    float* __restrict__ pmax, float* __restrict__ nmin, float* __restrict__ rmax) {
  __shared__ __align__(16) short As[BM * 64];   // 16 KB, linear [row][64]
  __shared__ __align__(16) short Bs[BM * 64];   // 16 KB
  __shared__ float s_sq_r[BM], s_sq_c[BM];
  __shared__ int   s_lb_r[BM], s_lb_c[BM];
  __shared__ float colred[3][4][BM];            // 6 KB cross-wave col combine

  // XCD-aware swizzle (2080 % 8 == 0, bijective) then upper-tri decode
  int t0 = blockIdx.x;
  int t = (t0 & 7) * (NTILES / 8) + (t0 >> 3);
  int bi = (int)((129.0f - sqrtf(16641.0f - 8.0f * (float)t)) * 0.5f);
  if (bi < 0) bi = 0;
  while (bi > 0 && tri_off(bi) > t) --bi;
  while (tri_off(bi + 1) <= t) ++bi;
  int bj = bi + (t - tri_off(bi));
  int brow = bi * BM, bcol = bj * BM;
  bool diag_blk = (bi == bj);

  int tid = threadIdx.x;
  int wid = tid >> 6, lane = tid & 63;
  int hi = lane >> 4, lo = lane & 15;

  if (tid < BM) {
    s_sq_r[tid] = sqn[brow + tid];
    s_lb_r[tid] = lab[brow + tid];
    s_sq_c[tid] = sqn[bcol + tid];
    s_lb_c[tid] = lab[bcol + tid];
  }

  f32x4 acc[2][8];
  #pragma unroll
  for (int a = 0; a < 2; ++a)
    #pragma unroll
    for (int b = 0; b < 8; ++b) acc[a][b] = (f32x4)(0.f);

  // staging lane constants: lane covers row (seg*8 + lane>>3), 16B chunk
  // (lane&7), fetched from global chunk ((lane&7) ^ (row&7)) so that
  // LDS[row][p] = G[row][p ^ (row&7)]  (both-sides swizzle, linear dest)
  int lrow = lane >> 3;
  int lchunk = (lane & 7) ^ lrow;
  size_t lane_goff = (size_t)lrow * DD + lchunk * 8;   // shorts
  const short* gA = fb + (size_t)brow * DD + lane_goff;
  const short* gB = fb + (size_t)bcol * DD + lane_goff;

  // read-side swizzled chunk: want G[row][C], C = ks*4+hi; row&7 == lo&7
  int cs0 = hi ^ (lo & 7);          // ks=0
  int cs1 = cs0 ^ 4;                // ks=1

  for (int kt = 0; kt < NKT; ++kt) {
    __syncthreads();   // prior tile's ds_reads done
    int kb = kt * BK;  // shorts
    #pragma unroll
    for (int i = 0; i < 4; ++i) {
      int seg = wid * 4 + i;
      gload16(gA + (size_t)seg * 8 * DD + kb, &As[seg * 512]);
      gload16(gB + (size_t)seg * 8 * DD + kb, &Bs[seg * 512]);
    }
    __syncthreads();   // staging visible (compiler drains vmcnt at barrier)
    #pragma unroll
    for (int ks = 0; ks < 2; ++ks) {
      int cs = ks ? cs1 : cs0;
      int a0r = wid * 32 + lo;
      s16x8 a0 = *(const s16x8*)&As[a0r * 64 + cs * 8];
      s16x8 a1 = *(const s16x8*)&As[(a0r + 16) * 64 + cs * 8];
      s16x8 bfr[8];
      #pragma unroll
      for (int fc = 0; fc < 8; ++fc)
        bfr[fc] = *(const s16x8*)&Bs[(fc * 16 + lo) * 64 + cs * 8];
      #pragma unroll
      for (int fc = 0; fc < 8; ++fc) {
        acc[0][fc] = __builtin_amdgcn_mfma_f32_16x16x32_bf16(a0, bfr[fc], acc[0][fc], 0, 0, 0);
        acc[1][fc] = __builtin_amdgcn_mfma_f32_16x16x32_bf16(a1, bfr[fc], acc[1][fc], 0, 0, 0);
      }
    }
  }

  // Epilogue: SQUARED distances + masked reductions (rows and, by symmetry, cols).
  const float FINF = __int_as_float(0x7f800000);
  float sqc[8]; int lbc[8];
  #pragma unroll
  for (int fc = 0; fc < 8; ++fc) {
    sqc[fc] = s_sq_c[fc * 16 + lo];
    lbc[fc] = s_lb_c[fc * 16 + lo];
  }
  float cvp[8], cvn[8], cvr[8];
  #pragma unroll
  for (int fc = 0; fc < 8; ++fc) { cvp[fc] = 0.f; cvn[fc] = FINF; cvr[fc] = 0.f; }

  #pragma unroll
  for (int fr = 0; fr < 2; ++fr) {
    #pragma unroll
    for (int rg = 0; rg < 4; ++rg) {
      int rt = wid * 32 + fr * 16 + hi * 4 + rg;
      float sqi = s_sq_r[rt];
      int   li  = s_lb_r[rt];
      float vp = 0.f, vn = FINF, vr = 0.f;
      #pragma unroll
      for (int fc = 0; fc < 8; ++fc) {
        float g = acc[fr][fc][rg];
        float v = fmaxf(sqi + sqc[fc] - 2.0f * g, 0.f);   // squared dist, clamped
        if (diag_blk && rt == fc * 16 + lo) v = 0.f;      // zero the diagonal
        bool same = (li == lbc[fc]);
        float vs = same ? v : 0.f;
        float vd = same ? FINF : v;
        vr = fmaxf(vr, v);   cvr[fc] = fmaxf(cvr[fc], v);
        vp = fmaxf(vp, vs);  cvp[fc] = fmaxf(cvp[fc], vs);
        vn = fminf(vn, vd);  cvn[fc] = fminf(cvn[fc], vd);
      }
      // reduce across the 16 lanes sharing this row (cols)
      #pragma unroll
      for (int m = 1; m < 16; m <<= 1) {
        vr = fmaxf(vr, __shfl_xor(vr, m));
        vp = fmaxf(vp, __shfl_xor(vp, m));
        vn = fminf(vn, __shfl_xor(vn, m));
      }
      if (lo == 0) {
        int gi = brow + rt;
        atomicMax((int*)&rmax[gi], __float_as_int(vr));
        atomicMax((int*)&pmax[gi], __float_as_int(vp));
        atomicMin((int*)&nmin[gi], __float_as_int(vn));
      }
    }
  }
  // column-side: combine across hi groups (rows) in-wave, then cross-wave via LDS
  #pragma unroll
  for (int fc = 0; fc < 8; ++fc) {
    #pragma unroll
    for (int m = 16; m < 64; m <<= 1) {
      cvr[fc] = fmaxf(cvr[fc], __shfl_xor(cvr[fc], m));
      cvp[fc] = fmaxf(cvp[fc], __shfl_xor(cvp[fc], m));
      cvn[fc] = fminf(cvn[fc], __shfl_xor(cvn[fc], m));
    }
    if (hi == 0) {
      int ct = fc * 16 + lo;
      colred[0][wid][ct] = cvp[fc];
      colred[1][wid][ct] = cvn[fc];
      colred[2][wid][ct] = cvr[fc];
    }
  }
  __syncthreads();
  if (tid < BM) {
    float p = colred[0][0][tid], n = colred[1][0][tid], r = colred[2][0][tid];
    #pragma unroll
    for (int w = 1; w < 4; ++w) {
      p = fmaxf(p, colred[0][w][tid]);
      n = fminf(n, colred[1][w][tid]);
      r = fmaxf(r, colred[2][w][tid]);
    }
    int gj = bcol + tid;
    atomicMax((int*)&pmax[gj], __float_as_int(p));
    atomicMin((int*)&nmin[gj], __float_as_int(n));
    atomicMax((int*)&rmax[gj], __float_as_int(r));
  }
}

__global__ __launch_bounds__(256) void finalize_kernel(
    const float* __restrict__ pmax, const float* __restrict__ nmin,
    const float* __restrict__ rmax, float* __restrict__ out) {
  int i = blockIdx.x * blockDim.x + threadIdx.x;
  if (i < NN) {
    out[2 * i]     = sqrtf(pmax[i]);                  // back to distance space
    out[2 * i + 1] = sqrtf(fminf(nmin[i], rmax[i]));  // no-negative fallback
  }
}

extern "C" void kernel_launch(void* const* d_in, const int* in_sizes, int n_in,
                              void* d_out, int out_size, void* d_ws, size_t ws_size,
                              hipStream_t stream) {
  const float* feat = (const float*)d_in[0];
  const int*   lab  = (const int*)d_in[1];
  float* out = (float*)d_out;

  char* ws = (char*)d_ws;
  short* fb   = (short*)ws;                                  // 8192*512*2 = 8388608 B
  float* sqn  = (float*)(ws + 8388608);                      // 32768 B
  float* pmax = (float*)(ws + 8388608 + 32768);              // 32768 B
  float* nmin = (float*)(ws + 8388608 + 2 * 32768);          // 32768 B
  float* rmax = (float*)(ws + 8388608 + 3 * 32768);          // 32768 B

  prep_kernel<<<NN / 4, 256, 0, stream>>>(feat, fb, sqn, pmax, nmin, rmax);
  tile_kernel<<<NTILES, 256, 0, stream>>>(fb, sqn, lab, pmax, nmin, rmax);
  finalize_kernel<<<(NN + 255) / 256, 256, 0, stream>>>(pmax, nmin, rmax, out);
}

// Round 7
// 112.426 us; speedup vs baseline: 1.6501x; 1.2809x over previous
//
#include <hip/hip_runtime.h>
#include <stdint.h>

#define NN 8192
#define DD 512
#define BM 128
#define BK 64             // bf16 elements per K-step = 128 B rows in LDS
#define NKT (DD / BK)     // 8
#define NB 64             // NN / BM
#define NTILES 2080       // NB*(NB+1)/2 upper-triangular tiles

typedef short s16x8 __attribute__((ext_vector_type(8)));
typedef float f32x4 __attribute__((ext_vector_type(4)));

static __device__ __forceinline__ short f2bf(float x) {
  union { float f; uint32_t u; } c; c.f = x;
  uint32_t r = c.u + 0x7fffu + ((c.u >> 16) & 1u);   // RNE
  return (short)(r >> 16);
}

static __device__ __forceinline__ int tri_off(int b) {
  return b * NB - (b * (b - 1)) / 2;
}

static __device__ __forceinline__ void gload16(const void* g, void* l) {
  __builtin_amdgcn_global_load_lds(
      (const __attribute__((address_space(1))) void*)g,
      (__attribute__((address_space(3))) void*)l, 16, 0, 0);
}

// 4 waves/block, one row per wave: fp32 -> bf16, sq-norm, init reductions.
__global__ __launch_bounds__(256) void prep_kernel(
    const float* __restrict__ f, short* __restrict__ fb,
    float* __restrict__ sqn, float* __restrict__ pmax,
    float* __restrict__ nmin, float* __restrict__ rmax) {
  int wid = threadIdx.x >> 6, lane = threadIdx.x & 63;
  int row = blockIdx.x * 4 + wid;
  const float4* src = (const float4*)(f + (size_t)row * DD);
  float4 v0 = src[lane * 2];
  float4 v1 = src[lane * 2 + 1];
  float s = v0.x*v0.x + v0.y*v0.y + v0.z*v0.z + v0.w*v0.w
          + v1.x*v1.x + v1.y*v1.y + v1.z*v1.z + v1.w*v1.w;
  s16x8 o;
  o[0]=f2bf(v0.x); o[1]=f2bf(v0.y); o[2]=f2bf(v0.z); o[3]=f2bf(v0.w);
  o[4]=f2bf(v1.x); o[5]=f2bf(v1.y); o[6]=f2bf(v1.z); o[7]=f2bf(v1.w);
  *(s16x8*)&fb[(size_t)row * DD + lane * 8] = o;
  #pragma unroll
  for (int m = 1; m < 64; m <<= 1) s += __shfl_xor(s, m);
  if (lane == 0) {
    sqn[row] = s;
    pmax[row] = 0.f;
    nmin[row] = __int_as_float(0x7f800000);   // +inf
    rmax[row] = 0.f;
  }
}

// Upper-triangular 128x128 tiles of F*F^T via bf16 MFMA + global_load_lds
// staging (linear LDS dest, swizzled global source + swizzled ds_read).
// (256,3): 3 waves/EU -> ~170-VGPR budget; 68 arch + 64 acc fits, NO spill.
// ((256,4) caps the unified file at 128 -> 64 arch + 64 acc -> epilogue
// spills 209 MB to scratch and costs +50 us. Measured R6.)
__global__ __launch_bounds__(256, 3) void tile_kernel(
    const short* __restrict__ fb, const float* __restrict__ sqn,
    const int* __restrict__ lab,
    float* __restrict__ pmax, float* __restrict__ nmin, float* __restrict__ rmax) {
  __shared__ __align__(16) short As[BM * 64];   // 16 KB, linear [row][64]
  __shared__ __align__(16) short Bs[BM * 64];   // 16 KB
  __shared__ float s_sq_r[BM], s_sq_c[BM];
  __shared__ int   s_lb_r[BM], s_lb_c[BM];
  __shared__ float colred[3][4][BM];            // 6 KB cross-wave col combine

  // XCD-aware swizzle (2080 % 8 == 0, bijective) then upper-tri decode
  int t0 = blockIdx.x;
  int t = (t0 & 7) * (NTILES / 8) + (t0 >> 3);
  int bi = (int)((129.0f - sqrtf(16641.0f - 8.0f * (float)t)) * 0.5f);
  if (bi < 0) bi = 0;
  while (bi > 0 && tri_off(bi) > t) --bi;
  while (tri_off(bi + 1) <= t) ++bi;
  int bj = bi + (t - tri_off(bi));
  int brow = bi * BM, bcol = bj * BM;
  bool diag_blk = (bi == bj);

  int tid = threadIdx.x;
  int wid = tid >> 6, lane = tid & 63;
  int hi = lane >> 4, lo = lane & 15;

  if (tid < BM) {
    s_sq_r[tid] = sqn[brow + tid];
    s_lb_r[tid] = lab[brow + tid];
    s_sq_c[tid] = sqn[bcol + tid];
    s_lb_c[tid] = lab[bcol + tid];
  }

  f32x4 acc[2][8];
  #pragma unroll
  for (int a = 0; a < 2; ++a)
    #pragma unroll
    for (int b = 0; b < 8; ++b) acc[a][b] = (f32x4)(0.f);

  // staging lane constants: lane covers row (seg*8 + lane>>3), 16B chunk
  // (lane&7), fetched from global chunk ((lane&7) ^ (row&7)) so that
  // LDS[row][p] = G[row][p ^ (row&7)]  (both-sides swizzle, linear dest)
  int lrow = lane >> 3;
  int lchunk = (lane & 7) ^ lrow;
  size_t lane_goff = (size_t)lrow * DD + lchunk * 8;   // shorts
  const short* gA = fb + (size_t)brow * DD + lane_goff;
  const short* gB = fb + (size_t)bcol * DD + lane_goff;

  // read-side swizzled chunk: want G[row][C], C = ks*4+hi; row&7 == lo&7
  int cs0 = hi ^ (lo & 7);          // ks=0
  int cs1 = cs0 ^ 4;                // ks=1

  for (int kt = 0; kt < NKT; ++kt) {
    __syncthreads();   // prior tile's ds_reads done
    int kb = kt * BK;  // shorts
    #pragma unroll
    for (int i = 0; i < 4; ++i) {
      int seg = wid * 4 + i;
      gload16(gA + (size_t)seg * 8 * DD + kb, &As[seg * 512]);
      gload16(gB + (size_t)seg * 8 * DD + kb, &Bs[seg * 512]);
    }
    __syncthreads();   // staging visible (compiler drains vmcnt at barrier)
    #pragma unroll
    for (int ks = 0; ks < 2; ++ks) {
      int cs = ks ? cs1 : cs0;
      int a0r = wid * 32 + lo;
      s16x8 a0 = *(const s16x8*)&As[a0r * 64 + cs * 8];
      s16x8 a1 = *(const s16x8*)&As[(a0r + 16) * 64 + cs * 8];
      s16x8 bfr[8];
      #pragma unroll
      for (int fc = 0; fc < 8; ++fc)
        bfr[fc] = *(const s16x8*)&Bs[(fc * 16 + lo) * 64 + cs * 8];
      #pragma unroll
      for (int fc = 0; fc < 8; ++fc) {
        acc[0][fc] = __builtin_amdgcn_mfma_f32_16x16x32_bf16(a0, bfr[fc], acc[0][fc], 0, 0, 0);
        acc[1][fc] = __builtin_amdgcn_mfma_f32_16x16x32_bf16(a1, bfr[fc], acc[1][fc], 0, 0, 0);
      }
    }
  }

  // Epilogue: SQUARED distances + masked reductions (rows and, by symmetry, cols).
  const float FINF = __int_as_float(0x7f800000);
  float sqc[8]; int lbc[8];
  #pragma unroll
  for (int fc = 0; fc < 8; ++fc) {
    sqc[fc] = s_sq_c[fc * 16 + lo];
    lbc[fc] = s_lb_c[fc * 16 + lo];
  }
  float cvp[8], cvn[8], cvr[8];
  #pragma unroll
  for (int fc = 0; fc < 8; ++fc) { cvp[fc] = 0.f; cvn[fc] = FINF; cvr[fc] = 0.f; }

  #pragma unroll
  for (int fr = 0; fr < 2; ++fr) {
    #pragma unroll
    for (int rg = 0; rg < 4; ++rg) {
      int rt = wid * 32 + fr * 16 + hi * 4 + rg;
      float sqi = s_sq_r[rt];
      int   li  = s_lb_r[rt];
      float vp = 0.f, vn = FINF, vr = 0.f;
      #pragma unroll
      for (int fc = 0; fc < 8; ++fc) {
        float g = acc[fr][fc][rg];
        float v = fmaxf(sqi + sqc[fc] - 2.0f * g, 0.f);   // squared dist, clamped
        if (diag_blk && rt == fc * 16 + lo) v = 0.f;      // zero the diagonal
        bool same = (li == lbc[fc]);
        float vs = same ? v : 0.f;
        float vd = same ? FINF : v;
        vr = fmaxf(vr, v);   cvr[fc] = fmaxf(cvr[fc], v);
        vp = fmaxf(vp, vs);  cvp[fc] = fmaxf(cvp[fc], vs);
        vn = fminf(vn, vd);  cvn[fc] = fminf(cvn[fc], vd);
      }
      // reduce across the 16 lanes sharing this row (cols)
      #pragma unroll
      for (int m = 1; m < 16; m <<= 1) {
        vr = fmaxf(vr, __shfl_xor(vr, m));
        vp = fmaxf(vp, __shfl_xor(vp, m));
        vn = fminf(vn, __shfl_xor(vn, m));
      }
      if (lo == 0) {
        int gi = brow + rt;
        atomicMax((int*)&rmax[gi], __float_as_int(vr));
        atomicMax((int*)&pmax[gi], __float_as_int(vp));
        atomicMin((int*)&nmin[gi], __float_as_int(vn));
      }
    }
  }
  // column-side: combine across hi groups (rows) in-wave, then cross-wave via LDS
  #pragma unroll
  for (int fc = 0; fc < 8; ++fc) {
    #pragma unroll
    for (int m = 16; m < 64; m <<= 1) {
      cvr[fc] = fmaxf(cvr[fc], __shfl_xor(cvr[fc], m));
      cvp[fc] = fmaxf(cvp[fc], __shfl_xor(cvp[fc], m));
      cvn[fc] = fminf(cvn[fc], __shfl_xor(cvn[fc], m));
    }
    if (hi == 0) {
      int ct = fc * 16 + lo;
      colred[0][wid][ct] = cvp[fc];
      colred[1][wid][ct] = cvn[fc];
      colred[2][wid][ct] = cvr[fc];
    }
  }
  __syncthreads();
  if (tid < BM) {
    float p = colred[0][0][tid], n = colred[1][0][tid], r = colred[2][0][tid];
    #pragma unroll
    for (int w = 1; w < 4; ++w) {
      p = fmaxf(p, colred[0][w][tid]);
      n = fminf(n, colred[1][w][tid]);
      r = fmaxf(r, colred[2][w][tid]);
    }
    int gj = bcol + tid;
    atomicMax((int*)&pmax[gj], __float_as_int(p));
    atomicMin((int*)&nmin[gj], __float_as_int(n));
    atomicMax((int*)&rmax[gj], __float_as_int(r));
  }
}

__global__ __launch_bounds__(256) void finalize_kernel(
    const float* __restrict__ pmax, const float* __restrict__ nmin,
    const float* __restrict__ rmax, float* __restrict__ out) {
  int i = blockIdx.x * blockDim.x + threadIdx.x;
  if (i < NN) {
    out[2 * i]     = sqrtf(pmax[i]);                  // back to distance space
    out[2 * i + 1] = sqrtf(fminf(nmin[i], rmax[i]));  // no-negative fallback
  }
}

extern "C" void kernel_launch(void* const* d_in, const int* in_sizes, int n_in,
                              void* d_out, int out_size, void* d_ws, size_t ws_size,
                              hipStream_t stream) {
  const float* feat = (const float*)d_in[0];
  const int*   lab  = (const int*)d_in[1];
  float* out = (float*)d_out;

  char* ws = (char*)d_ws;
  short* fb   = (short*)ws;                                  // 8192*512*2 = 8388608 B
  float* sqn  = (float*)(ws + 8388608);                      // 32768 B
  float* pmax = (float*)(ws + 8388608 + 32768);              // 32768 B
  float* nmin = (float*)(ws + 8388608 + 2 * 32768);          // 32768 B
  float* rmax = (float*)(ws + 8388608 + 3 * 32768);          // 32768 B

  prep_kernel<<<NN / 4, 256, 0, stream>>>(feat, fb, sqn, pmax, nmin, rmax);
  tile_kernel<<<NTILES, 256, 0, stream>>>(fb, sqn, lab, pmax, nmin, rmax);
  finalize_kernel<<<(NN + 255) / 256, 256, 0, stream>>>(pmax, nmin, rmax, out);
}

// Round 8
// 83.203 us; speedup vs baseline: 2.2296x; 1.3512x over previous
//
#include <hip/hip_runtime.h>
#include <stdint.h>

#define NN 8192
#define DD 512
#define BM 128
#define BK 64             // bf16 elements per K-step = 128 B rows in LDS
#define NKT (DD / BK)     // 8
#define NB 64             // NN / BM
#define NTILES 2080       // NB*(NB+1)/2 upper-triangular tiles

typedef short s16x8 __attribute__((ext_vector_type(8)));
typedef float f32x4 __attribute__((ext_vector_type(4)));

static __device__ __forceinline__ short f2bf(float x) {
  union { float f; uint32_t u; } c; c.f = x;
  uint32_t r = c.u + 0x7fffu + ((c.u >> 16) & 1u);   // RNE
  return (short)(r >> 16);
}

static __device__ __forceinline__ int tri_off(int b) {
  return b * NB - (b * (b - 1)) / 2;
}

static __device__ __forceinline__ void gload16(const void* g, void* l) {
  __builtin_amdgcn_global_load_lds(
      (const __attribute__((address_space(1))) void*)g,
      (__attribute__((address_space(3))) void*)l, 16, 0, 0);
}

// 4 waves/block, one row per wave: fp32 -> bf16, sq-norm, init reductions.
__global__ __launch_bounds__(256) void prep_kernel(
    const float* __restrict__ f, short* __restrict__ fb,
    float* __restrict__ sqn, float* __restrict__ pmax,
    float* __restrict__ nmin, float* __restrict__ rmax) {
  int wid = threadIdx.x >> 6, lane = threadIdx.x & 63;
  int row = blockIdx.x * 4 + wid;
  const float4* src = (const float4*)(f + (size_t)row * DD);
  float4 v0 = src[lane * 2];
  float4 v1 = src[lane * 2 + 1];
  float s = v0.x*v0.x + v0.y*v0.y + v0.z*v0.z + v0.w*v0.w
          + v1.x*v1.x + v1.y*v1.y + v1.z*v1.z + v1.w*v1.w;
  s16x8 o;
  o[0]=f2bf(v0.x); o[1]=f2bf(v0.y); o[2]=f2bf(v0.z); o[3]=f2bf(v0.w);
  o[4]=f2bf(v1.x); o[5]=f2bf(v1.y); o[6]=f2bf(v1.z); o[7]=f2bf(v1.w);
  *(s16x8*)&fb[(size_t)row * DD + lane * 8] = o;
  #pragma unroll
  for (int m = 1; m < 64; m <<= 1) s += __shfl_xor(s, m);
  if (lane == 0) {
    sqn[row] = s;
    pmax[row] = 0.f;
    nmin[row] = __int_as_float(0x7f800000);   // +inf
    rmax[row] = 0.f;
  }
}

// Upper-triangular 128x128 tiles of F*F^T via bf16 MFMA + global_load_lds
// staging (linear LDS dest, swizzled global source + swizzled ds_read).
// EXACT R2 structure (82 us verified). Single change vs R2: epilogue reduces
// in SQUARED-distance space (sqrtf moved to finalize). No hoisting -- R7's
// sqc/lbc register hoist regressed to 103 us (16 regs live across K-loop,
// VGPR 68->84, scratch-like +110 MB traffic).
__global__ __launch_bounds__(256, 3) void tile_kernel(
    const short* __restrict__ fb, const float* __restrict__ sqn,
    const int* __restrict__ lab,
    float* __restrict__ pmax, float* __restrict__ nmin, float* __restrict__ rmax) {
  __shared__ __align__(16) short As[BM * 64];   // 16 KB, linear [row][64]
  __shared__ __align__(16) short Bs[BM * 64];   // 16 KB
  __shared__ float s_sq_r[BM], s_sq_c[BM];
  __shared__ int   s_lb_r[BM], s_lb_c[BM];
  __shared__ float colred[3][4][BM];            // 6 KB cross-wave col combine

  // XCD-aware swizzle (2080 % 8 == 0, bijective) then upper-tri decode
  int t0 = blockIdx.x;
  int t = (t0 & 7) * (NTILES / 8) + (t0 >> 3);
  int bi = (int)((129.0f - sqrtf(16641.0f - 8.0f * (float)t)) * 0.5f);
  if (bi < 0) bi = 0;
  while (bi > 0 && tri_off(bi) > t) --bi;
  while (tri_off(bi + 1) <= t) ++bi;
  int bj = bi + (t - tri_off(bi));
  int brow = bi * BM, bcol = bj * BM;

  int tid = threadIdx.x;
  int wid = tid >> 6, lane = tid & 63;
  int hi = lane >> 4, lo = lane & 15;

  if (tid < BM) {
    s_sq_r[tid] = sqn[brow + tid];
    s_lb_r[tid] = lab[brow + tid];
    s_sq_c[tid] = sqn[bcol + tid];
    s_lb_c[tid] = lab[bcol + tid];
  }

  f32x4 acc[2][8];
  #pragma unroll
  for (int a = 0; a < 2; ++a)
    #pragma unroll
    for (int b = 0; b < 8; ++b) acc[a][b] = (f32x4)(0.f);

  // staging lane constants: lane covers row (seg*8 + lane>>3), 16B chunk
  // (lane&7), fetched from global chunk ((lane&7) ^ (row&7)) so that
  // LDS[row][p] = G[row][p ^ (row&7)]  (both-sides swizzle, linear dest)
  int lrow = lane >> 3;
  int lchunk = (lane & 7) ^ lrow;
  size_t lane_goff = (size_t)lrow * DD + lchunk * 8;   // shorts
  const short* gA = fb + (size_t)brow * DD + lane_goff;
  const short* gB = fb + (size_t)bcol * DD + lane_goff;

  // read-side swizzled chunk: want G[row][C], C = ks*4+hi; row&7 == lo&7
  int cs0 = hi ^ (lo & 7);          // ks=0
  int cs1 = cs0 ^ 4;                // ks=1

  for (int kt = 0; kt < NKT; ++kt) {
    __syncthreads();   // prior tile's ds_reads done
    int kb = kt * BK;  // shorts
    #pragma unroll
    for (int i = 0; i < 4; ++i) {
      int seg = wid * 4 + i;
      gload16(gA + (size_t)seg * 8 * DD + kb, &As[seg * 512]);
      gload16(gB + (size_t)seg * 8 * DD + kb, &Bs[seg * 512]);
    }
    __syncthreads();   // staging visible (compiler drains vmcnt at barrier)
    #pragma unroll
    for (int ks = 0; ks < 2; ++ks) {
      int cs = ks ? cs1 : cs0;
      int a0r = wid * 32 + lo;
      s16x8 a0 = *(const s16x8*)&As[a0r * 64 + cs * 8];
      s16x8 a1 = *(const s16x8*)&As[(a0r + 16) * 64 + cs * 8];
      s16x8 bfr[8];
      #pragma unroll
      for (int fc = 0; fc < 8; ++fc)
        bfr[fc] = *(const s16x8*)&Bs[(fc * 16 + lo) * 64 + cs * 8];
      #pragma unroll
      for (int fc = 0; fc < 8; ++fc) {
        acc[0][fc] = __builtin_amdgcn_mfma_f32_16x16x32_bf16(a0, bfr[fc], acc[0][fc], 0, 0, 0);
        acc[1][fc] = __builtin_amdgcn_mfma_f32_16x16x32_bf16(a1, bfr[fc], acc[1][fc], 0, 0, 0);
      }
    }
  }

  // Epilogue: SQUARED distances + masked reductions (rows and, by symmetry, cols).
  // Identical to R2 except no sqrtf (monotone, deferred to finalize).
  const float FINF = __int_as_float(0x7f800000);
  float cvp[8], cvn[8], cvr[8];
  #pragma unroll
  for (int fc = 0; fc < 8; ++fc) { cvp[fc] = 0.f; cvn[fc] = FINF; cvr[fc] = 0.f; }

  #pragma unroll
  for (int fr = 0; fr < 2; ++fr) {
    #pragma unroll
    for (int rg = 0; rg < 4; ++rg) {
      int rt = wid * 32 + fr * 16 + hi * 4 + rg;
      int gi = brow + rt;
      float sqi = s_sq_r[rt];
      int   li  = s_lb_r[rt];
      float vp = 0.f, vn = FINF, vr = 0.f;
      #pragma unroll
      for (int fc = 0; fc < 8; ++fc) {
        int ct = fc * 16 + lo;
        int gj = bcol + ct;
        float g = acc[fr][fc][rg];
        float v = fmaxf(sqi + s_sq_c[ct] - 2.0f * g, 0.f);   // squared dist
        if (gi == gj) v = 0.f;                               // zero the diagonal
        bool same = (li == s_lb_c[ct]);
        vr = fmaxf(vr, v);
        cvr[fc] = fmaxf(cvr[fc], v);
        if (same) {
          vp = fmaxf(vp, v);
          cvp[fc] = fmaxf(cvp[fc], v);
        } else {
          vn = fminf(vn, v);
          cvn[fc] = fminf(cvn[fc], v);
        }
      }
      // reduce across the 16 lanes sharing this row (cols)
      #pragma unroll
      for (int m = 1; m < 16; m <<= 1) {
        vr = fmaxf(vr, __shfl_xor(vr, m));
        vp = fmaxf(vp, __shfl_xor(vp, m));
        vn = fminf(vn, __shfl_xor(vn, m));
      }
      if (lo == 0) {
        atomicMax((int*)&rmax[gi], __float_as_int(vr));
        atomicMax((int*)&pmax[gi], __float_as_int(vp));
        atomicMin((int*)&nmin[gi], __float_as_int(vn));
      }
    }
  }
  // column-side: combine across hi groups (rows) in-wave, then cross-wave via LDS
  #pragma unroll
  for (int fc = 0; fc < 8; ++fc) {
    #pragma unroll
    for (int m = 16; m < 64; m <<= 1) {
      cvr[fc] = fmaxf(cvr[fc], __shfl_xor(cvr[fc], m));
      cvp[fc] = fmaxf(cvp[fc], __shfl_xor(cvp[fc], m));
      cvn[fc] = fminf(cvn[fc], __shfl_xor(cvn[fc], m));
    }
    if (hi == 0) {
      int ct = fc * 16 + lo;
      colred[0][wid][ct] = cvp[fc];
      colred[1][wid][ct] = cvn[fc];
      colred[2][wid][ct] = cvr[fc];
    }
  }
  __syncthreads();
  if (tid < BM) {
    float p = colred[0][0][tid], n = colred[1][0][tid], r = colred[2][0][tid];
    #pragma unroll
    for (int w = 1; w < 4; ++w) {
      p = fmaxf(p, colred[0][w][tid]);
      n = fminf(n, colred[1][w][tid]);
      r = fmaxf(r, colred[2][w][tid]);
    }
    int gj = bcol + tid;
    atomicMax((int*)&pmax[gj], __float_as_int(p));
    atomicMin((int*)&nmin[gj], __float_as_int(n));
    atomicMax((int*)&rmax[gj], __float_as_int(r));
  }
}

__global__ __launch_bounds__(256) void finalize_kernel(
    const float* __restrict__ pmax, const float* __restrict__ nmin,
    const float* __restrict__ rmax, float* __restrict__ out) {
  int i = blockIdx.x * blockDim.x + threadIdx.x;
  if (i < NN) {
    out[2 * i]     = sqrtf(pmax[i]);                  // back to distance space
    out[2 * i + 1] = sqrtf(fminf(nmin[i], rmax[i]));  // no-negative fallback
  }
}

extern "C" void kernel_launch(void* const* d_in, const int* in_sizes, int n_in,
                              void* d_out, int out_size, void* d_ws, size_t ws_size,
                              hipStream_t stream) {
  const float* feat = (const float*)d_in[0];
  const int*   lab  = (const int*)d_in[1];
  float* out = (float*)d_out;

  char* ws = (char*)d_ws;
  short* fb   = (short*)ws;                                  // 8192*512*2 = 8388608 B
  float* sqn  = (float*)(ws + 8388608);                      // 32768 B
  float* pmax = (float*)(ws + 8388608 + 32768);              // 32768 B
  float* nmin = (float*)(ws + 8388608 + 2 * 32768);          // 32768 B
  float* rmax = (float*)(ws + 8388608 + 3 * 32768);          // 32768 B

  prep_kernel<<<NN / 4, 256, 0, stream>>>(feat, fb, sqn, pmax, nmin, rmax);
  tile_kernel<<<NTILES, 256, 0, stream>>>(fb, sqn, lab, pmax, nmin, rmax);
  finalize_kernel<<<(NN + 255) / 256, 256, 0, stream>>>(pmax, nmin, rmax, out);
}

// Round 9
// 74.315 us; speedup vs baseline: 2.4963x; 1.1196x over previous
//
#include <hip/hip_runtime.h>
#include <stdint.h>

#define NN 8192
#define DD 512
#define BM 128
#define BK 64             // bf16 elements per K-step = 128 B rows in LDS
#define NKT (DD / BK)     // 8
#define NB 64             // NN / BM
#define NTILES 2080       // NB*(NB+1)/2 upper-triangular tiles

typedef short s16x8 __attribute__((ext_vector_type(8)));
typedef float f32x4 __attribute__((ext_vector_type(4)));

static __device__ __forceinline__ short f2bf(float x) {
  union { float f; uint32_t u; } c; c.f = x;
  uint32_t r = c.u + 0x7fffu + ((c.u >> 16) & 1u);   // RNE
  return (short)(r >> 16);
}

static __device__ __forceinline__ int tri_off(int b) {
  return b * NB - (b * (b - 1)) / 2;
}

static __device__ __forceinline__ void gload16(const void* g, void* l) {
  __builtin_amdgcn_global_load_lds(
      (const __attribute__((address_space(1))) void*)g,
      (__attribute__((address_space(3))) void*)l, 16, 0, 0);
}

// 4 waves/block, one row per wave: fp32 -> bf16, sq-norm, init reductions.
__global__ __launch_bounds__(256) void prep_kernel(
    const float* __restrict__ f, short* __restrict__ fb,
    float* __restrict__ sqn, float* __restrict__ pmax,
    float* __restrict__ nmin) {
  int wid = threadIdx.x >> 6, lane = threadIdx.x & 63;
  int row = blockIdx.x * 4 + wid;
  const float4* src = (const float4*)(f + (size_t)row * DD);
  float4 v0 = src[lane * 2];
  float4 v1 = src[lane * 2 + 1];
  float s = v0.x*v0.x + v0.y*v0.y + v0.z*v0.z + v0.w*v0.w
          + v1.x*v1.x + v1.y*v1.y + v1.z*v1.z + v1.w*v1.w;
  s16x8 o;
  o[0]=f2bf(v0.x); o[1]=f2bf(v0.y); o[2]=f2bf(v0.z); o[3]=f2bf(v0.w);
  o[4]=f2bf(v1.x); o[5]=f2bf(v1.y); o[6]=f2bf(v1.z); o[7]=f2bf(v1.w);
  *(s16x8*)&fb[(size_t)row * DD + lane * 8] = o;
  #pragma unroll
  for (int m = 1; m < 64; m <<= 1) s += __shfl_xor(s, m);
  if (lane == 0) {
    sqn[row] = s;
    pmax[row] = 0.f;
    nmin[row] = __int_as_float(0x7f800000);   // +inf
  }
}

// Upper-triangular 128x128 tiles of F*F^T via bf16 MFMA + global_load_lds
// staging (linear LDS dest, swizzled global source + swizzled ds_read).
// R8 structure (70.6 us verified). Single change vs R8: rmax reduction is
// REMOVED -- it is mathematically redundant: nmin==+inf means the whole row
// is same-label, so row-max == pmax. finalize substitutes pmax for the
// empty-negative fallback. Cuts 1/3 of epilogue reduce ops and atomics.
// LDS 38912 B -> 4 blocks/CU fit at runtime; compiler still allocs for (256,3).
__global__ __launch_bounds__(256, 3) void tile_kernel(
    const short* __restrict__ fb, const float* __restrict__ sqn,
    const int* __restrict__ lab,
    float* __restrict__ pmax, float* __restrict__ nmin) {
  __shared__ __align__(16) short As[BM * 64];   // 16 KB, linear [row][64]
  __shared__ __align__(16) short Bs[BM * 64];   // 16 KB
  __shared__ float s_sq_r[BM], s_sq_c[BM];
  __shared__ int   s_lb_r[BM], s_lb_c[BM];
  __shared__ float colred[2][4][BM];            // 4 KB cross-wave col combine

  // XCD-aware swizzle (2080 % 8 == 0, bijective) then upper-tri decode
  int t0 = blockIdx.x;
  int t = (t0 & 7) * (NTILES / 8) + (t0 >> 3);
  int bi = (int)((129.0f - sqrtf(16641.0f - 8.0f * (float)t)) * 0.5f);
  if (bi < 0) bi = 0;
  while (bi > 0 && tri_off(bi) > t) --bi;
  while (tri_off(bi + 1) <= t) ++bi;
  int bj = bi + (t - tri_off(bi));
  int brow = bi * BM, bcol = bj * BM;

  int tid = threadIdx.x;
  int wid = tid >> 6, lane = tid & 63;
  int hi = lane >> 4, lo = lane & 15;

  if (tid < BM) {
    s_sq_r[tid] = sqn[brow + tid];
    s_lb_r[tid] = lab[brow + tid];
    s_sq_c[tid] = sqn[bcol + tid];
    s_lb_c[tid] = lab[bcol + tid];
  }

  f32x4 acc[2][8];
  #pragma unroll
  for (int a = 0; a < 2; ++a)
    #pragma unroll
    for (int b = 0; b < 8; ++b) acc[a][b] = (f32x4)(0.f);

  // staging lane constants: lane covers row (seg*8 + lane>>3), 16B chunk
  // (lane&7), fetched from global chunk ((lane&7) ^ (row&7)) so that
  // LDS[row][p] = G[row][p ^ (row&7)]  (both-sides swizzle, linear dest)
  int lrow = lane >> 3;
  int lchunk = (lane & 7) ^ lrow;
  size_t lane_goff = (size_t)lrow * DD + lchunk * 8;   // shorts
  const short* gA = fb + (size_t)brow * DD + lane_goff;
  const short* gB = fb + (size_t)bcol * DD + lane_goff;

  // read-side swizzled chunk: want G[row][C], C = ks*4+hi; row&7 == lo&7
  int cs0 = hi ^ (lo & 7);          // ks=0
  int cs1 = cs0 ^ 4;                // ks=1

  for (int kt = 0; kt < NKT; ++kt) {
    __syncthreads();   // prior tile's ds_reads done
    int kb = kt * BK;  // shorts
    #pragma unroll
    for (int i = 0; i < 4; ++i) {
      int seg = wid * 4 + i;
      gload16(gA + (size_t)seg * 8 * DD + kb, &As[seg * 512]);
      gload16(gB + (size_t)seg * 8 * DD + kb, &Bs[seg * 512]);
    }
    __syncthreads();   // staging visible (compiler drains vmcnt at barrier)
    #pragma unroll
    for (int ks = 0; ks < 2; ++ks) {
      int cs = ks ? cs1 : cs0;
      int a0r = wid * 32 + lo;
      s16x8 a0 = *(const s16x8*)&As[a0r * 64 + cs * 8];
      s16x8 a1 = *(const s16x8*)&As[(a0r + 16) * 64 + cs * 8];
      s16x8 bfr[8];
      #pragma unroll
      for (int fc = 0; fc < 8; ++fc)
        bfr[fc] = *(const s16x8*)&Bs[(fc * 16 + lo) * 64 + cs * 8];
      #pragma unroll
      for (int fc = 0; fc < 8; ++fc) {
        acc[0][fc] = __builtin_amdgcn_mfma_f32_16x16x32_bf16(a0, bfr[fc], acc[0][fc], 0, 0, 0);
        acc[1][fc] = __builtin_amdgcn_mfma_f32_16x16x32_bf16(a1, bfr[fc], acc[1][fc], 0, 0, 0);
      }
    }
  }

  // Epilogue: SQUARED distances + masked max/min (rows and, by symmetry, cols).
  const float FINF = __int_as_float(0x7f800000);
  float cvp[8], cvn[8];
  #pragma unroll
  for (int fc = 0; fc < 8; ++fc) { cvp[fc] = 0.f; cvn[fc] = FINF; }

  #pragma unroll
  for (int fr = 0; fr < 2; ++fr) {
    #pragma unroll
    for (int rg = 0; rg < 4; ++rg) {
      int rt = wid * 32 + fr * 16 + hi * 4 + rg;
      int gi = brow + rt;
      float sqi = s_sq_r[rt];
      int   li  = s_lb_r[rt];
      float vp = 0.f, vn = FINF;
      #pragma unroll
      for (int fc = 0; fc < 8; ++fc) {
        int ct = fc * 16 + lo;
        int gj = bcol + ct;
        float g = acc[fr][fc][rg];
        float v = fmaxf(sqi + s_sq_c[ct] - 2.0f * g, 0.f);   // squared dist
        if (gi == gj) v = 0.f;                               // zero the diagonal
        bool same = (li == s_lb_c[ct]);
        if (same) {
          vp = fmaxf(vp, v);
          cvp[fc] = fmaxf(cvp[fc], v);
        } else {
          vn = fminf(vn, v);
          cvn[fc] = fminf(cvn[fc], v);
        }
      }
      // reduce across the 16 lanes sharing this row (cols)
      #pragma unroll
      for (int m = 1; m < 16; m <<= 1) {
        vp = fmaxf(vp, __shfl_xor(vp, m));
        vn = fminf(vn, __shfl_xor(vn, m));
      }
      if (lo == 0) {
        atomicMax((int*)&pmax[gi], __float_as_int(vp));
        atomicMin((int*)&nmin[gi], __float_as_int(vn));
      }
    }
  }
  // column-side: combine across hi groups (rows) in-wave, then cross-wave via LDS
  #pragma unroll
  for (int fc = 0; fc < 8; ++fc) {
    #pragma unroll
    for (int m = 16; m < 64; m <<= 1) {
      cvp[fc] = fmaxf(cvp[fc], __shfl_xor(cvp[fc], m));
      cvn[fc] = fminf(cvn[fc], __shfl_xor(cvn[fc], m));
    }
    if (hi == 0) {
      int ct = fc * 16 + lo;
      colred[0][wid][ct] = cvp[fc];
      colred[1][wid][ct] = cvn[fc];
    }
  }
  __syncthreads();
  if (tid < BM) {
    float p = colred[0][0][tid], n = colred[1][0][tid];
    #pragma unroll
    for (int w = 1; w < 4; ++w) {
      p = fmaxf(p, colred[0][w][tid]);
      n = fminf(n, colred[1][w][tid]);
    }
    int gj = bcol + tid;
    atomicMax((int*)&pmax[gj], __float_as_int(p));
    atomicMin((int*)&nmin[gj], __float_as_int(n));
  }
}

__global__ __launch_bounds__(256) void finalize_kernel(
    const float* __restrict__ pmax, const float* __restrict__ nmin,
    float* __restrict__ out) {
  int i = blockIdx.x * blockDim.x + threadIdx.x;
  if (i < NN) {
    const float FINF = __int_as_float(0x7f800000);
    float p = pmax[i];
    float n = nmin[i];
    // empty-negative fallback: axis_max == pmax when the whole row is same-label
    if (n == FINF) n = p;
    out[2 * i]     = sqrtf(p);
    out[2 * i + 1] = sqrtf(n);
  }
}

extern "C" void kernel_launch(void* const* d_in, const int* in_sizes, int n_in,
                              void* d_out, int out_size, void* d_ws, size_t ws_size,
                              hipStream_t stream) {
  const float* feat = (const float*)d_in[0];
  const int*   lab  = (const int*)d_in[1];
  float* out = (float*)d_out;

  char* ws = (char*)d_ws;
  short* fb   = (short*)ws;                                  // 8192*512*2 = 8388608 B
  float* sqn  = (float*)(ws + 8388608);                      // 32768 B
  float* pmax = (float*)(ws + 8388608 + 32768);              // 32768 B
  float* nmin = (float*)(ws + 8388608 + 2 * 32768);          // 32768 B

  prep_kernel<<<NN / 4, 256, 0, stream>>>(feat, fb, sqn, pmax, nmin);
  tile_kernel<<<NTILES, 256, 0, stream>>>(fb, sqn, lab, pmax, nmin);
  finalize_kernel<<<(NN + 255) / 256, 256, 0, stream>>>(pmax, nmin, out);
}